// Round 1
// baseline (503.730 us; speedup 1.0000x reference)
//
#include <hip/hip_runtime.h>

// HierarchicalMemory v3: wave-per-row streaming GEMV + LDS row-cache.
//   M[p,q] = clip(F*Mp[p,q] + (LR*a[p])*b[q], -1, 1), masked block-triangular;
//   5 attractor iterations with progressively frozen rows Rt={400,340,280,200,100}.
// M is constant across iterations, and stream-0 rows (p<100, full 400 cols) are
// re-read 5x by the fused design. v3 caches the first CROWS=96 rows POST-clip in
// LDS during iteration 0 (153.6 KB), serving iterations 1-4 from LDS: M traffic
// drops 790 MB -> 476 MB and the Hebbian recompute disappears for those visits.
// Cost: 1 block/CU (was 2). Compensated by 2-row-deep global prefetch (same
// 16-rows-in-flight/CU as v2) and by issuing the streamed-tail prefetch BEFORE
// the LDS phase so HBM latency hides under cached-row dots.
// Lane l owns columns [4l..4l+3] and [256+4l..4l+3]; dot-reduce is 6 DPP adds.

#define PDIM 400
#define CROWS 96            // stream-0 rows cached post-clip in LDS (96*1600B)
#define FORGET 0.9999f
#define LRATE  0.5f
#define DECAY  0.8f
#define SLOPE  0.01f

__device__ __forceinline__ float leaky_clip(float x) {
    x = fminf(fmaxf(x, -1.0f), 1.0f);
    return x > 0.0f ? x : SLOPE * x;
}
__device__ __forceinline__ float clamp1(float x) {
    return fminf(fmaxf(x, -1.0f), 1.0f);
}

// first masked f4-chunk of row p (chunk = 4-float column group)
__device__ __forceinline__ int c4beg(int p) {
    return (p < 100) ? 0 : (p < 200) ? 25 : (p < 280) ? 50 : (p < 340) ? 70 : 85;
}

// wave64 sum via DPP: stays on the VALU pipe (no ds_swizzle / LDS traffic).
__device__ __forceinline__ float wave_sum(float x) {
    x += __int_as_float(__builtin_amdgcn_update_dpp(0, __float_as_int(x), 0xB1,  0xf, 0xf, true));
    x += __int_as_float(__builtin_amdgcn_update_dpp(0, __float_as_int(x), 0x4E,  0xf, 0xf, true));
    x += __int_as_float(__builtin_amdgcn_update_dpp(0, __float_as_int(x), 0x141, 0xf, 0xf, true));
    x += __int_as_float(__builtin_amdgcn_update_dpp(0, __float_as_int(x), 0x140, 0xf, 0xf, true));
    x += __int_as_float(__builtin_amdgcn_update_dpp(0, __float_as_int(x), 0x142, 0xf, 0xf, true));
    x += __int_as_float(__builtin_amdgcn_update_dpp(0, __float_as_int(x), 0x143, 0xf, 0xf, true));
    return __int_as_float(__builtin_amdgcn_readlane(__float_as_int(x), 63));
}

// predicated masked row load (global), zeros outside mask / past R
__device__ __forceinline__ void load_row(const float* __restrict__ Mb,
                                         int p, int R, int l,
                                         int& c4, float4& A, float4& B) {
    const float4 z4 = make_float4(0.f, 0.f, 0.f, 0.f);
    c4 = 0; A = z4; B = z4;
    if (p < R) {
        c4 = c4beg(p);
        const float* __restrict__ row = Mb + (size_t)p * PDIM;
        if (l >= c4)                A = *(const float4*)(row + 4 * l);
        if (l < 36 && 64 + l >= c4) B = *(const float4*)(row + 256 + 4 * l);
    }
}

__global__ __launch_bounds__(512, 2)
void hier_mem_kernel(const float* __restrict__ M_prev,
                     const float* __restrict__ p_inf,
                     const float* __restrict__ p_gen,
                     const float* __restrict__ query,
                     float* __restrict__ out)
{
    __shared__ float s_mc[CROWS][PDIM];   // 153,600 B post-clip M cache
    __shared__ float s_h[2][PDIM];
    __shared__ float s_la[PDIM];

    const int b   = blockIdx.x;
    const int tid = threadIdx.x;
    const int l   = tid & 63;   // lane
    const int wid = tid >> 6;   // wave 0..7
    const float* __restrict__ Mb = M_prev + (size_t)b * PDIM * PDIM;

    if (tid < PDIM) {
        const float pi = p_inf[b * PDIM + tid];
        const float pg = p_gen[b * PDIM + tid];
        s_la[tid]   = LRATE * (pi - pg);
        s_h[0][tid] = leaky_clip(query[b * PDIM + tid]);
    }

    // register-resident b-vector for this lane's fixed columns
    const float4 z4 = make_float4(0.f, 0.f, 0.f, 0.f);
    const float4* __restrict__ pi4 = (const float4*)(p_inf + (size_t)b * PDIM);
    const float4* __restrict__ pg4 = (const float4*)(p_gen + (size_t)b * PDIM);
    float4 vA, vB = z4;
    {
        const float4 x = pi4[l], y = pg4[l];
        vA = make_float4(x.x + y.x, x.y + y.y, x.z + y.z, x.w + y.w);
        if (l < 36) {
            const float4 u = pi4[64 + l], v = pg4[64 + l];
            vB = make_float4(u.x + v.x, u.y + v.y, u.z + v.z, u.w + v.w);
        }
    }
    __syncthreads();

    // ---------- iteration 0: stream all 400 rows; cache rows [0,CROWS) ----------
    {
        const float* __restrict__ hcur = s_h[0];
        float* __restrict__ hnew = s_h[1];
        float4 hA = *(const float4*)(hcur + 4 * l);
        float4 hB = z4;
        if (l < 36) hB = *(const float4*)(hcur + 256 + 4 * l);

        int p = wid;
        int c0, c1; float4 A0, B0, A1, B1;
        load_row(Mb, p,     PDIM, l, c0, A0, B0);
        load_row(Mb, p + 8, PDIM, l, c1, A1, B1);

        while (p < PDIM) {
            int c2; float4 A2, B2;
            load_row(Mb, p + 16, PDIM, l, c2, A2, B2);

            const float la = s_la[p];   // wave-uniform LDS broadcast
            float acc = 0.f;
            float4 mA = z4, mB = z4;
            if (l >= c0) {
                mA.x = clamp1(fmaf(FORGET, A0.x, la * vA.x));
                mA.y = clamp1(fmaf(FORGET, A0.y, la * vA.y));
                mA.z = clamp1(fmaf(FORGET, A0.z, la * vA.z));
                mA.w = clamp1(fmaf(FORGET, A0.w, la * vA.w));
                acc = fmaf(mA.x, hA.x, fmaf(mA.y, hA.y, fmaf(mA.z, hA.z, mA.w * hA.w)));
            }
            if (l < 36 && 64 + l >= c0) {
                mB.x = clamp1(fmaf(FORGET, B0.x, la * vB.x));
                mB.y = clamp1(fmaf(FORGET, B0.y, la * vB.y));
                mB.z = clamp1(fmaf(FORGET, B0.z, la * vB.z));
                mB.w = clamp1(fmaf(FORGET, B0.w, la * vB.w));
                acc = fmaf(mB.x, hB.x, fmaf(mB.y, hB.y, fmaf(mB.z, hB.z, fmaf(mB.w, hB.w, acc))));
            }
            if (p < CROWS) {   // stream-0 rows: c0==0, all lanes valid
                *(float4*)&s_mc[p][4 * l] = mA;
                if (l < 36) *(float4*)&s_mc[p][256 + 4 * l] = mB;
            }

            const float tot = wave_sum(acc);
            if (l == 0) {
                hnew[p] = leaky_clip(fmaf(DECAY, hcur[p], tot));
            }

            p += 8; c0 = c1; A0 = A1; B0 = B1; c1 = c2; A1 = A2; B1 = B2;
        }
        __syncthreads();   // R=400: no frozen rows
    }

    // ---------- iterations 1..4: LDS-cached head + streamed tail ----------
    int cur = 1;
    const int Rt[4] = {340, 280, 200, 100};
    #pragma unroll
    for (int t = 0; t < 4; ++t) {
        const int R = Rt[t];
        const float* __restrict__ hcur = s_h[cur];
        float* __restrict__ hnew = s_h[cur ^ 1];

        float4 hA = *(const float4*)(hcur + 4 * l);
        float4 hB = z4;
        if (l < 36) hB = *(const float4*)(hcur + 256 + 4 * l);

        // kick off global prefetch for the streamed tail FIRST (hides HBM
        // latency under the LDS-cached phase below)
        int sp = CROWS + wid;
        int c0, c1; float4 A0, B0, A1, B1;
        load_row(Mb, sp,     R, l, c0, A0, B0);
        load_row(Mb, sp + 8, R, l, c1, A1, B1);

        // cached rows [0,CROWS) from LDS: post-clip M, no recompute, 1-ahead
        {
            int p = wid;
            float4 KA = *(const float4*)&s_mc[p][4 * l];
            float4 KB = z4;
            if (l < 36) KB = *(const float4*)&s_mc[p][256 + 4 * l];
            while (p < CROWS) {
                const int pn = p + 8;
                float4 NA = z4, NB = z4;
                if (pn < CROWS) {
                    NA = *(const float4*)&s_mc[pn][4 * l];
                    if (l < 36) NB = *(const float4*)&s_mc[pn][256 + 4 * l];
                }
                // KB/hB are zero for lanes >=36 -> unconditional dot is safe
                float acc = fmaf(KA.x, hA.x, fmaf(KA.y, hA.y, fmaf(KA.z, hA.z, KA.w * hA.w)));
                acc = fmaf(KB.x, hB.x, fmaf(KB.y, hB.y, fmaf(KB.z, hB.z, fmaf(KB.w, hB.w, acc))));
                const float tot = wave_sum(acc);
                if (l == 0) {
                    hnew[p] = leaky_clip(fmaf(DECAY, hcur[p], tot));
                }
                p = pn; KA = NA; KB = NB;
            }
        }

        // streamed rows [CROWS, R), 2-row-deep prefetch
        while (sp < R) {
            int c2; float4 A2, B2;
            load_row(Mb, sp + 16, R, l, c2, A2, B2);

            const float la = s_la[sp];
            float acc = 0.f;
            if (l >= c0) {
                float m0 = clamp1(fmaf(FORGET, A0.x, la * vA.x));
                float m1 = clamp1(fmaf(FORGET, A0.y, la * vA.y));
                float m2 = clamp1(fmaf(FORGET, A0.z, la * vA.z));
                float m3 = clamp1(fmaf(FORGET, A0.w, la * vA.w));
                acc = fmaf(m0, hA.x, fmaf(m1, hA.y, fmaf(m2, hA.z, m3 * hA.w)));
            }
            if (l < 36 && 64 + l >= c0) {
                float m0 = clamp1(fmaf(FORGET, B0.x, la * vB.x));
                float m1 = clamp1(fmaf(FORGET, B0.y, la * vB.y));
                float m2 = clamp1(fmaf(FORGET, B0.z, la * vB.z));
                float m3 = clamp1(fmaf(FORGET, B0.w, la * vB.w));
                acc = fmaf(m0, hB.x, fmaf(m1, hB.y, fmaf(m2, hB.z, fmaf(m3, hB.w, acc))));
            }

            const float tot = wave_sum(acc);
            if (l == 0) {
                hnew[sp] = leaky_clip(fmaf(DECAY, hcur[sp], tot));
            }

            sp += 8; c0 = c1; A0 = A1; B0 = B1; c1 = c2; A1 = A2; B1 = B2;
        }

        // frozen rows carry through
        if (tid >= R && tid < PDIM) hnew[tid] = hcur[tid];
        __syncthreads();
        cur ^= 1;
    }

    if (tid < PDIM) {
        out[b * PDIM + tid] = s_h[cur][tid];
    }
}

extern "C" void kernel_launch(void* const* d_in, const int* in_sizes, int n_in,
                              void* d_out, int out_size, void* d_ws, size_t ws_size,
                              hipStream_t stream) {
    const float* M_prev = (const float*)d_in[0];
    const float* p_inf  = (const float*)d_in[1];
    const float* p_gen  = (const float*)d_in[2];
    const float* query  = (const float*)d_in[3];
    float* out = (float*)d_out;

    const int B = in_sizes[1] / PDIM;   // 512
    hipLaunchKernelGGL(hier_mem_kernel, dim3(B), dim3(512), 0, stream,
                       M_prev, p_inf, p_gen, query, out);
}

// Round 2
// 481.843 us; speedup vs baseline: 1.0454x; 1.0454x over previous
//
#include <hip/hip_runtime.h>

// HierarchicalMemory v4: wave-per-row streaming GEMV, packed-fp32 VALU,
// 46-row LDS cache at FULL occupancy (2 blocks/CU).
//   M[p,q] = clip(F*Mp[p,q] + (LR*a[p])*b[q], -1, 1), masked block-triangular;
//   5 attractor iterations with progressively frozen rows Rt={400,340,280,200,100}.
// v3 post-mortem: L3 absorbs all re-reads (198MB masked < 256MB), so the big
// LDS cache at halved occupancy was neutral. v4 is VALU/latency-targeted:
//  - v_pk_mul_f32 / v_pk_fma_f32 (VOP3P) halve the Hebbian+dot issue count
//    (hipcc does not form packed fp32 from scalar code); clamp stays v_med3.
//  - 46-row post-clip cache (73.6KB/block; 2x78.4KB < 160KB LDS/CU) keeps a
//    free slice of the re-read/recompute savings WITHOUT the occupancy tax.
//  - 2-deep prefetch in iter 0 (HBM-cold), 1-deep in L3-resident tails,
//    tail prefetch issued before the LDS-cached phase for overlap.
// Lane l owns columns [4l..4l+3] and [256+4l..256+4l+3]; dot-reduce is 6 DPP adds.

#define PDIM 400
#define CROWS 46            // rows cached post-clip in LDS (46*1600B = 73.6KB)
#define FORGET 0.9999f
#define LRATE  0.5f
#define DECAY  0.8f
#define SLOPE  0.01f

typedef float f32x2 __attribute__((ext_vector_type(2)));
union V4 { float4 f4; f32x2 h2[2]; };

__device__ __forceinline__ float leaky_clip(float x) {
    x = fminf(fmaxf(x, -1.0f), 1.0f);
    return x > 0.0f ? x : SLOPE * x;
}
__device__ __forceinline__ float clamp1(float x) {   // -> v_med3_f32
    return fminf(fmaxf(x, -1.0f), 1.0f);
}
__device__ __forceinline__ f32x2 pk_mul(f32x2 a, f32x2 b) {
    f32x2 d;
    asm("v_pk_mul_f32 %0, %1, %2" : "=v"(d) : "v"(a), "v"(b));
    return d;
}
__device__ __forceinline__ f32x2 pk_fma(f32x2 a, f32x2 b, f32x2 c) {
    f32x2 d;
    asm("v_pk_fma_f32 %0, %1, %2, %3" : "=v"(d) : "v"(a), "v"(b), "v"(c));
    return d;
}
__device__ __forceinline__ f32x2 clamp2(f32x2 x) {
    x.x = clamp1(x.x); x.y = clamp1(x.y); return x;
}

// first masked f4-chunk of row p (chunk = 4-float column group)
__device__ __forceinline__ int c4beg(int p) {
    return (p < 100) ? 0 : (p < 200) ? 25 : (p < 280) ? 50 : (p < 340) ? 70 : 85;
}

// wave64 sum via DPP: stays on the VALU pipe (no ds_swizzle / LDS traffic).
__device__ __forceinline__ float wave_sum(float x) {
    x += __int_as_float(__builtin_amdgcn_update_dpp(0, __float_as_int(x), 0xB1,  0xf, 0xf, true));
    x += __int_as_float(__builtin_amdgcn_update_dpp(0, __float_as_int(x), 0x4E,  0xf, 0xf, true));
    x += __int_as_float(__builtin_amdgcn_update_dpp(0, __float_as_int(x), 0x141, 0xf, 0xf, true));
    x += __int_as_float(__builtin_amdgcn_update_dpp(0, __float_as_int(x), 0x140, 0xf, 0xf, true));
    x += __int_as_float(__builtin_amdgcn_update_dpp(0, __float_as_int(x), 0x142, 0xf, 0xf, true));
    x += __int_as_float(__builtin_amdgcn_update_dpp(0, __float_as_int(x), 0x143, 0xf, 0xf, true));
    return __int_as_float(__builtin_amdgcn_readlane(__float_as_int(x), 63));
}

// predicated masked row load (global), zeros outside mask / past R
__device__ __forceinline__ void load_row(const float* __restrict__ Mb,
                                         int p, int R, int l,
                                         int& c4, V4& A, V4& B) {
    A.f4 = make_float4(0.f, 0.f, 0.f, 0.f);
    B.f4 = A.f4;
    c4 = 0;
    if (p < R) {
        c4 = c4beg(p);
        const float* __restrict__ row = Mb + (size_t)p * PDIM;
        if (l >= c4)                A.f4 = *(const float4*)(row + 4 * l);
        if (l < 36 && 64 + l >= c4) B.f4 = *(const float4*)(row + 256 + 4 * l);
    }
}

__global__ __launch_bounds__(512, 4)
void hier_mem_kernel(const float* __restrict__ M_prev,
                     const float* __restrict__ p_inf,
                     const float* __restrict__ p_gen,
                     const float* __restrict__ query,
                     float* __restrict__ out)
{
    __shared__ float s_mc[CROWS][PDIM];   // 73,600 B post-clip M cache
    __shared__ float s_h[2][PDIM];
    __shared__ float s_la[PDIM];

    const int b   = blockIdx.x;
    const int tid = threadIdx.x;
    const int l   = tid & 63;   // lane
    const int wid = tid >> 6;   // wave 0..7
    const float* __restrict__ Mb = M_prev + (size_t)b * PDIM * PDIM;

    if (tid < PDIM) {
        const float pi = p_inf[b * PDIM + tid];
        const float pg = p_gen[b * PDIM + tid];
        s_la[tid]   = LRATE * (pi - pg);
        s_h[0][tid] = leaky_clip(query[b * PDIM + tid]);
    }

    // register-resident b-vector for this lane's fixed columns
    const float4 z4 = make_float4(0.f, 0.f, 0.f, 0.f);
    const float4* __restrict__ pi4 = (const float4*)(p_inf + (size_t)b * PDIM);
    const float4* __restrict__ pg4 = (const float4*)(p_gen + (size_t)b * PDIM);
    V4 vA, vB; vB.f4 = z4;
    {
        const float4 x = pi4[l], y = pg4[l];
        vA.f4 = make_float4(x.x + y.x, x.y + y.y, x.z + y.z, x.w + y.w);
        if (l < 36) {
            const float4 u = pi4[64 + l], v = pg4[64 + l];
            vB.f4 = make_float4(u.x + v.x, u.y + v.y, u.z + v.z, u.w + v.w);
        }
    }
    const f32x2 F2 = {FORGET, FORGET};
    __syncthreads();

    // ---------- iteration 0: stream all 400 rows; cache rows [0,CROWS) ----------
    {
        const float* __restrict__ hcur = s_h[0];
        float* __restrict__ hnew = s_h[1];
        V4 hA, hB; hB.f4 = z4;
        hA.f4 = *(const float4*)(hcur + 4 * l);
        if (l < 36) hB.f4 = *(const float4*)(hcur + 256 + 4 * l);

        int p = wid;
        int c0, c1; V4 A0, B0, A1, B1;
        load_row(Mb, p,     PDIM, l, c0, A0, B0);
        load_row(Mb, p + 8, PDIM, l, c1, A1, B1);

        while (p < PDIM) {
            int c2; V4 A2, B2;
            load_row(Mb, p + 16, PDIM, l, c2, A2, B2);

            const float la = s_la[p];   // wave-uniform LDS broadcast
            const f32x2 la2 = {la, la};
            f32x2 acc2 = {0.f, 0.f};
            V4 mA, mB; mA.f4 = z4; mB.f4 = z4;
            if (l >= c0) {
                mA.h2[0] = clamp2(pk_fma(F2, A0.h2[0], pk_mul(la2, vA.h2[0])));
                mA.h2[1] = clamp2(pk_fma(F2, A0.h2[1], pk_mul(la2, vA.h2[1])));
                acc2 = pk_fma(mA.h2[0], hA.h2[0], acc2);
                acc2 = pk_fma(mA.h2[1], hA.h2[1], acc2);
            }
            if (l < 36 && 64 + l >= c0) {
                mB.h2[0] = clamp2(pk_fma(F2, B0.h2[0], pk_mul(la2, vB.h2[0])));
                mB.h2[1] = clamp2(pk_fma(F2, B0.h2[1], pk_mul(la2, vB.h2[1])));
                acc2 = pk_fma(mB.h2[0], hB.h2[0], acc2);
                acc2 = pk_fma(mB.h2[1], hB.h2[1], acc2);
            }
            if (p < CROWS) {   // cached rows have c0==0
                *(float4*)&s_mc[p][4 * l] = mA.f4;
                if (l < 36) *(float4*)&s_mc[p][256 + 4 * l] = mB.f4;
            }

            const float tot = wave_sum(acc2.x + acc2.y);
            if (l == 0) {
                hnew[p] = leaky_clip(fmaf(DECAY, hcur[p], tot));
            }

            p += 8; c0 = c1; A0 = A1; B0 = B1; c1 = c2; A1 = A2; B1 = B2;
        }
        __syncthreads();   // R=400: no frozen rows
    }

    // ---------- iterations 1..4: LDS-cached head + streamed tail ----------
    int cur = 1;
    const int Rt[4] = {340, 280, 200, 100};
    #pragma unroll
    for (int t = 0; t < 4; ++t) {
        const int R = Rt[t];
        const float* __restrict__ hcur = s_h[cur];
        float* __restrict__ hnew = s_h[cur ^ 1];

        V4 hA, hB; hB.f4 = z4;
        hA.f4 = *(const float4*)(hcur + 4 * l);
        if (l < 36) hB.f4 = *(const float4*)(hcur + 256 + 4 * l);

        // kick off global prefetch for the streamed tail FIRST (hides L3/HBM
        // latency under the LDS-cached phase below)
        int sp = CROWS + wid;
        int c0; V4 A0, B0;
        load_row(Mb, sp, R, l, c0, A0, B0);

        // cached rows [0,CROWS) from LDS: post-clip M, dot only, 1-ahead
        {
            int p = wid;
            V4 KA, KB; KB.f4 = z4;
            KA.f4 = *(const float4*)&s_mc[p][4 * l];
            if (l < 36) KB.f4 = *(const float4*)&s_mc[p][256 + 4 * l];
            while (p < CROWS) {
                const int pn = p + 8;
                V4 NA, NB; NA.f4 = z4; NB.f4 = z4;
                if (pn < CROWS) {
                    NA.f4 = *(const float4*)&s_mc[pn][4 * l];
                    if (l < 36) NB.f4 = *(const float4*)&s_mc[pn][256 + 4 * l];
                }
                // KB/hB are zero for lanes >=36 -> unconditional dot is safe
                f32x2 acc2 = pk_fma(KA.h2[0], hA.h2[0],
                             pk_fma(KA.h2[1], hA.h2[1],
                             pk_fma(KB.h2[0], hB.h2[0],
                             pk_mul(KB.h2[1], hB.h2[1]))));
                const float tot = wave_sum(acc2.x + acc2.y);
                if (l == 0) {
                    hnew[p] = leaky_clip(fmaf(DECAY, hcur[p], tot));
                }
                p = pn; KA = NA; KB = NB;
            }
        }

        // streamed rows [CROWS, R), 1-deep prefetch (L3-resident, short latency)
        while (sp < R) {
            int c1n; V4 A1, B1;
            load_row(Mb, sp + 8, R, l, c1n, A1, B1);

            const float la = s_la[sp];
            const f32x2 la2 = {la, la};
            f32x2 acc2 = {0.f, 0.f};
            if (l >= c0) {
                f32x2 m0 = clamp2(pk_fma(F2, A0.h2[0], pk_mul(la2, vA.h2[0])));
                f32x2 m1 = clamp2(pk_fma(F2, A0.h2[1], pk_mul(la2, vA.h2[1])));
                acc2 = pk_fma(m0, hA.h2[0], acc2);
                acc2 = pk_fma(m1, hA.h2[1], acc2);
            }
            if (l < 36 && 64 + l >= c0) {
                f32x2 m0 = clamp2(pk_fma(F2, B0.h2[0], pk_mul(la2, vB.h2[0])));
                f32x2 m1 = clamp2(pk_fma(F2, B0.h2[1], pk_mul(la2, vB.h2[1])));
                acc2 = pk_fma(m0, hB.h2[0], acc2);
                acc2 = pk_fma(m1, hB.h2[1], acc2);
            }

            const float tot = wave_sum(acc2.x + acc2.y);
            if (l == 0) {
                hnew[sp] = leaky_clip(fmaf(DECAY, hcur[sp], tot));
            }

            sp += 8; c0 = c1n; A0 = A1; B0 = B1;
        }

        // frozen rows carry through
        if (tid >= R && tid < PDIM) hnew[tid] = hcur[tid];
        __syncthreads();
        cur ^= 1;
    }

    if (tid < PDIM) {
        out[b * PDIM + tid] = s_h[cur][tid];
    }
}

extern "C" void kernel_launch(void* const* d_in, const int* in_sizes, int n_in,
                              void* d_out, int out_size, void* d_ws, size_t ws_size,
                              hipStream_t stream) {
    const float* M_prev = (const float*)d_in[0];
    const float* p_inf  = (const float*)d_in[1];
    const float* p_gen  = (const float*)d_in[2];
    const float* query  = (const float*)d_in[3];
    float* out = (float*)d_out;

    const int B = in_sizes[1] / PDIM;   // 512
    hipLaunchKernelGGL(hier_mem_kernel, dim3(B), dim3(512), 0, stream,
                       M_prev, p_inf, p_gen, query, out);
}

// Round 3
// 473.464 us; speedup vs baseline: 1.0639x; 1.0177x over previous
//
#include <hip/hip_runtime.h>

// HierarchicalMemory v5: wave-per-row streaming GEMV, packed-fp32 VALU,
// two-tier on-chip row cache (32 rows in VGPRs + 46 rows in LDS) at full
// occupancy (2 blocks/CU), 2-deep prefetch everywhere.
//   M[p,q] = clip(F*Mp[p,q] + (LR*a[p])*b[q], -1, 1), masked block-triangular;
//   5 attractor iterations, frozen-row schedule Rt={400,340,280,200,100}.
// v4 post-mortem: L3 re-read stream (441 MB @ ~14 TB/s) is co-dominant with
// the mandatory 198 MB HBM cold read. LDS cache is maxed at 78.4 KB/block;
// v5 taps the second on-chip pool: 32 spare VGPRs/lane = 64 KB/block.
//  - rows [0,32): post-clip M cached in registers (4 rows/wave, statically
//    indexed unrolled loops -> no scratch), zero traffic in iters 1-4.
//  - rows [32,78): post-clip M cached in LDS (73.6 KB).
//  - rows [78,R): streamed from L3 with 2-deep prefetch, Hebbian recomputed.
// Phase order per iteration: tail prefetch first, then reg rows (pure VALU,
// hides the prefetch latency), then LDS rows, then tail.
// Lane l owns columns [4l..4l+3] and [256+4l..256+4l+3]; reduce = 6 DPP adds.

#define PDIM 400
#define RREG 4              // register-cached rows: [0, 8*RREG) = [0,32)
#define LROW0 32
#define LROWN 78            // LDS-cached rows [32,78): 46 rows * 1600B = 73.6KB
#define FORGET 0.9999f
#define LRATE  0.5f
#define DECAY  0.8f
#define SLOPE  0.01f

typedef float f32x2 __attribute__((ext_vector_type(2)));
union V4 { float4 f4; f32x2 h2[2]; };

__device__ __forceinline__ float leaky_clip(float x) {
    x = fminf(fmaxf(x, -1.0f), 1.0f);
    return x > 0.0f ? x : SLOPE * x;
}
__device__ __forceinline__ float clamp1(float x) {   // -> v_med3_f32
    return fminf(fmaxf(x, -1.0f), 1.0f);
}
__device__ __forceinline__ f32x2 pk_mul(f32x2 a, f32x2 b) {
    f32x2 d;
    asm("v_pk_mul_f32 %0, %1, %2" : "=v"(d) : "v"(a), "v"(b));
    return d;
}
__device__ __forceinline__ f32x2 pk_fma(f32x2 a, f32x2 b, f32x2 c) {
    f32x2 d;
    asm("v_pk_fma_f32 %0, %1, %2, %3" : "=v"(d) : "v"(a), "v"(b), "v"(c));
    return d;
}
__device__ __forceinline__ f32x2 clamp2(f32x2 x) {
    x.x = clamp1(x.x); x.y = clamp1(x.y); return x;
}

// first masked f4-chunk of row p (chunk = 4-float column group)
__device__ __forceinline__ int c4beg(int p) {
    return (p < 100) ? 0 : (p < 200) ? 25 : (p < 280) ? 50 : (p < 340) ? 70 : 85;
}

// wave64 sum via DPP: stays on the VALU pipe (no ds_swizzle / LDS traffic).
__device__ __forceinline__ float wave_sum(float x) {
    x += __int_as_float(__builtin_amdgcn_update_dpp(0, __float_as_int(x), 0xB1,  0xf, 0xf, true));
    x += __int_as_float(__builtin_amdgcn_update_dpp(0, __float_as_int(x), 0x4E,  0xf, 0xf, true));
    x += __int_as_float(__builtin_amdgcn_update_dpp(0, __float_as_int(x), 0x141, 0xf, 0xf, true));
    x += __int_as_float(__builtin_amdgcn_update_dpp(0, __float_as_int(x), 0x140, 0xf, 0xf, true));
    x += __int_as_float(__builtin_amdgcn_update_dpp(0, __float_as_int(x), 0x142, 0xf, 0xf, true));
    x += __int_as_float(__builtin_amdgcn_update_dpp(0, __float_as_int(x), 0x143, 0xf, 0xf, true));
    return __int_as_float(__builtin_amdgcn_readlane(__float_as_int(x), 63));
}

// predicated masked row load (global), zeros outside mask / past R
__device__ __forceinline__ void load_row(const float* __restrict__ Mb,
                                         int p, int R, int l,
                                         int& c4, V4& A, V4& B) {
    A.f4 = make_float4(0.f, 0.f, 0.f, 0.f);
    B.f4 = A.f4;
    c4 = 0;
    if (p < R) {
        c4 = c4beg(p);
        const float* __restrict__ row = Mb + (size_t)p * PDIM;
        if (l >= c4)                A.f4 = *(const float4*)(row + 4 * l);
        if (l < 36 && 64 + l >= c4) B.f4 = *(const float4*)(row + 256 + 4 * l);
    }
}

__global__ __launch_bounds__(512, 4)
void hier_mem_kernel(const float* __restrict__ M_prev,
                     const float* __restrict__ p_inf,
                     const float* __restrict__ p_gen,
                     const float* __restrict__ query,
                     float* __restrict__ out)
{
    __shared__ float s_mc[LROWN - LROW0][PDIM];   // 73,600 B post-clip M cache
    __shared__ float s_h[2][PDIM];
    __shared__ float s_la[PDIM];

    const int b   = blockIdx.x;
    const int tid = threadIdx.x;
    const int l   = tid & 63;   // lane
    const int wid = tid >> 6;   // wave 0..7
    const float* __restrict__ Mb = M_prev + (size_t)b * PDIM * PDIM;

    if (tid < PDIM) {
        const float pi = p_inf[b * PDIM + tid];
        const float pg = p_gen[b * PDIM + tid];
        s_la[tid]   = LRATE * (pi - pg);
        s_h[0][tid] = leaky_clip(query[b * PDIM + tid]);
    }

    // register-resident b-vector for this lane's fixed columns
    const float4 z4 = make_float4(0.f, 0.f, 0.f, 0.f);
    const float4* __restrict__ pi4 = (const float4*)(p_inf + (size_t)b * PDIM);
    const float4* __restrict__ pg4 = (const float4*)(p_gen + (size_t)b * PDIM);
    V4 vA, vB; vB.f4 = z4;
    {
        const float4 x = pi4[l], y = pg4[l];
        vA.f4 = make_float4(x.x + y.x, x.y + y.y, x.z + y.z, x.w + y.w);
        if (l < 36) {
            const float4 u = pi4[64 + l], v = pg4[64 + l];
            vB.f4 = make_float4(u.x + v.x, u.y + v.y, u.z + v.z, u.w + v.w);
        }
    }
    const f32x2 F2 = {FORGET, FORGET};

    V4 rA[RREG], rB[RREG];   // per-wave register row cache (rows wid+8k, k<RREG)

    __syncthreads();

    // ---------- iteration 0: stream all 400 rows; fill reg + LDS caches ----------
    {
        const float* __restrict__ hcur = s_h[0];
        float* __restrict__ hnew = s_h[1];
        V4 hA, hB; hB.f4 = z4;
        hA.f4 = *(const float4*)(hcur + 4 * l);
        if (l < 36) hB.f4 = *(const float4*)(hcur + 256 + 4 * l);

        int p = wid;
        int c0, c1; V4 A0, B0, A1, B1;
        load_row(Mb, p,     PDIM, l, c0, A0, B0);
        load_row(Mb, p + 8, PDIM, l, c1, A1, B1);

        // rows [0,32): compute + fill register cache (static indices)
        #pragma unroll
        for (int k = 0; k < RREG; ++k) {
            int c2; V4 A2, B2;
            load_row(Mb, p + 16, PDIM, l, c2, A2, B2);

            const float la = s_la[p];
            const f32x2 la2 = {la, la};
            V4 mA, mB; mA.f4 = z4; mB.f4 = z4;
            // p < 32 -> c0 == 0: A valid on all lanes, B on lanes < 36
            mA.h2[0] = clamp2(pk_fma(F2, A0.h2[0], pk_mul(la2, vA.h2[0])));
            mA.h2[1] = clamp2(pk_fma(F2, A0.h2[1], pk_mul(la2, vA.h2[1])));
            if (l < 36) {
                mB.h2[0] = clamp2(pk_fma(F2, B0.h2[0], pk_mul(la2, vB.h2[0])));
                mB.h2[1] = clamp2(pk_fma(F2, B0.h2[1], pk_mul(la2, vB.h2[1])));
            }
            rA[k] = mA; rB[k] = mB;

            f32x2 acc2 = pk_fma(mA.h2[0], hA.h2[0],
                         pk_fma(mA.h2[1], hA.h2[1],
                         pk_fma(mB.h2[0], hB.h2[0],
                         pk_mul(mB.h2[1], hB.h2[1]))));
            const float tot = wave_sum(acc2.x + acc2.y);
            if (l == 0) {
                hnew[p] = leaky_clip(fmaf(DECAY, hcur[p], tot));
            }
            p += 8; c0 = c1; A0 = A1; B0 = B1; c1 = c2; A1 = A2; B1 = B2;
        }

        // rows [32,400): stream; write LDS cache for p < 78
        while (p < PDIM) {
            int c2; V4 A2, B2;
            load_row(Mb, p + 16, PDIM, l, c2, A2, B2);

            const float la = s_la[p];
            const f32x2 la2 = {la, la};
            f32x2 acc2 = {0.f, 0.f};
            V4 mA, mB; mA.f4 = z4; mB.f4 = z4;
            if (l >= c0) {
                mA.h2[0] = clamp2(pk_fma(F2, A0.h2[0], pk_mul(la2, vA.h2[0])));
                mA.h2[1] = clamp2(pk_fma(F2, A0.h2[1], pk_mul(la2, vA.h2[1])));
                acc2 = pk_fma(mA.h2[0], hA.h2[0], acc2);
                acc2 = pk_fma(mA.h2[1], hA.h2[1], acc2);
            }
            if (l < 36 && 64 + l >= c0) {
                mB.h2[0] = clamp2(pk_fma(F2, B0.h2[0], pk_mul(la2, vB.h2[0])));
                mB.h2[1] = clamp2(pk_fma(F2, B0.h2[1], pk_mul(la2, vB.h2[1])));
                acc2 = pk_fma(mB.h2[0], hB.h2[0], acc2);
                acc2 = pk_fma(mB.h2[1], hB.h2[1], acc2);
            }
            if (p < LROWN) {   // rows 32..77: c0==0, all lanes valid
                *(float4*)&s_mc[p - LROW0][4 * l] = mA.f4;
                if (l < 36) *(float4*)&s_mc[p - LROW0][256 + 4 * l] = mB.f4;
            }

            const float tot = wave_sum(acc2.x + acc2.y);
            if (l == 0) {
                hnew[p] = leaky_clip(fmaf(DECAY, hcur[p], tot));
            }

            p += 8; c0 = c1; A0 = A1; B0 = B1; c1 = c2; A1 = A2; B1 = B2;
        }
        __syncthreads();   // R=400: no frozen rows
    }

    // ---------- iterations 1..4: reg rows + LDS rows + streamed tail ----------
    int cur = 1;
    const int Rt[4] = {340, 280, 200, 100};
    #pragma unroll
    for (int t = 0; t < 4; ++t) {
        const int R = Rt[t];
        const float* __restrict__ hcur = s_h[cur];
        float* __restrict__ hnew = s_h[cur ^ 1];

        V4 hA, hB; hB.f4 = z4;
        hA.f4 = *(const float4*)(hcur + 4 * l);
        if (l < 36) hB.f4 = *(const float4*)(hcur + 256 + 4 * l);

        // kick off 2-deep global prefetch for the streamed tail FIRST
        int sp = LROWN + wid;
        int c0, c1; V4 A0, B0, A1, B1;
        load_row(Mb, sp,     R, l, c0, A0, B0);
        load_row(Mb, sp + 8, R, l, c1, A1, B1);

        // register-cached rows [0,32): pure VALU, hides prefetch latency
        #pragma unroll
        for (int k = 0; k < RREG; ++k) {
            const int p = wid + 8 * k;
            f32x2 acc2 = pk_fma(rA[k].h2[0], hA.h2[0],
                         pk_fma(rA[k].h2[1], hA.h2[1],
                         pk_fma(rB[k].h2[0], hB.h2[0],
                         pk_mul(rB[k].h2[1], hB.h2[1]))));
            const float tot = wave_sum(acc2.x + acc2.y);
            if (l == 0) {
                hnew[p] = leaky_clip(fmaf(DECAY, hcur[p], tot));
            }
        }

        // LDS-cached rows [32,78): post-clip M, dot only, 1-ahead
        {
            int p = LROW0 + wid;
            V4 KA, KB; KB.f4 = z4;
            KA.f4 = *(const float4*)&s_mc[p - LROW0][4 * l];
            if (l < 36) KB.f4 = *(const float4*)&s_mc[p - LROW0][256 + 4 * l];
            while (p < LROWN) {
                const int pn = p + 8;
                V4 NA, NB; NA.f4 = z4; NB.f4 = z4;
                if (pn < LROWN) {
                    NA.f4 = *(const float4*)&s_mc[pn - LROW0][4 * l];
                    if (l < 36) NB.f4 = *(const float4*)&s_mc[pn - LROW0][256 + 4 * l];
                }
                // KB/hB are zero for lanes >=36 -> unconditional dot is safe
                f32x2 acc2 = pk_fma(KA.h2[0], hA.h2[0],
                             pk_fma(KA.h2[1], hA.h2[1],
                             pk_fma(KB.h2[0], hB.h2[0],
                             pk_mul(KB.h2[1], hB.h2[1]))));
                const float tot = wave_sum(acc2.x + acc2.y);
                if (l == 0) {
                    hnew[p] = leaky_clip(fmaf(DECAY, hcur[p], tot));
                }
                p = pn; KA = NA; KB = NB;
            }
        }

        // streamed rows [78, R), 2-deep prefetch
        while (sp < R) {
            int c2; V4 A2, B2;
            load_row(Mb, sp + 16, R, l, c2, A2, B2);

            const float la = s_la[sp];
            const f32x2 la2 = {la, la};
            f32x2 acc2 = {0.f, 0.f};
            if (l >= c0) {
                f32x2 m0 = clamp2(pk_fma(F2, A0.h2[0], pk_mul(la2, vA.h2[0])));
                f32x2 m1 = clamp2(pk_fma(F2, A0.h2[1], pk_mul(la2, vA.h2[1])));
                acc2 = pk_fma(m0, hA.h2[0], acc2);
                acc2 = pk_fma(m1, hA.h2[1], acc2);
            }
            if (l < 36 && 64 + l >= c0) {
                f32x2 m0 = clamp2(pk_fma(F2, B0.h2[0], pk_mul(la2, vB.h2[0])));
                f32x2 m1 = clamp2(pk_fma(F2, B0.h2[1], pk_mul(la2, vB.h2[1])));
                acc2 = pk_fma(m0, hB.h2[0], acc2);
                acc2 = pk_fma(m1, hB.h2[1], acc2);
            }

            const float tot = wave_sum(acc2.x + acc2.y);
            if (l == 0) {
                hnew[sp] = leaky_clip(fmaf(DECAY, hcur[sp], tot));
            }

            sp += 8; c0 = c1; A0 = A1; B0 = B1; c1 = c2; A1 = A2; B1 = B2;
        }

        // frozen rows carry through
        if (tid >= R && tid < PDIM) hnew[tid] = hcur[tid];
        __syncthreads();
        cur ^= 1;
    }

    if (tid < PDIM) {
        out[b * PDIM + tid] = s_h[cur][tid];
    }
}

extern "C" void kernel_launch(void* const* d_in, const int* in_sizes, int n_in,
                              void* d_out, int out_size, void* d_ws, size_t ws_size,
                              hipStream_t stream) {
    const float* M_prev = (const float*)d_in[0];
    const float* p_inf  = (const float*)d_in[1];
    const float* p_gen  = (const float*)d_in[2];
    const float* query  = (const float*)d_in[3];
    float* out = (float*)d_out;

    const int B = in_sizes[1] / PDIM;   // 512
    hipLaunchKernelGGL(hier_mem_kernel, dim3(B), dim3(512), 0, stream,
                       M_prev, p_inf, p_gen, query, out);
}